// Round 9
// baseline (1362.369 us; speedup 1.0000x reference)
//
#include <hip/hip_runtime.h>
#include <cstdint>

typedef _Float16 f16;
typedef f16   f16x8 __attribute__((ext_vector_type(8)));
typedef f16   f16x4 __attribute__((ext_vector_type(4)));
typedef float f32x4 __attribute__((ext_vector_type(4)));
typedef float f32x8 __attribute__((ext_vector_type(8)));
typedef int   i32x4 __attribute__((ext_vector_type(4)));
typedef signed char c8x8 __attribute__((ext_vector_type(8)));
typedef unsigned int u32;

// Problem dims: B=2, S=128, DIN=768, PPOS=256, DCAT=2048, H=1024
// N_pairs = 32768, e rows = 256.

// workspace layout (bytes)
static constexpr size_t OFF_E16  = 0;                       // 256*1024 f16      = 0.5 MB
static constexpr size_t OFF_W0P  = 524288;                  // 16384*1024 f16    = 33.5 MB
static constexpr size_t OFF_UV   = 34078720;                // 256*16384 f32     = 16.8 MB
static constexpr size_t OFF_B0   = 50855936;                // 8192 f32
static constexpr size_t OFF_W1P  = 50888704;                // 6144*2048 i8      = 12.6 MB
static constexpr size_t OFF_B1   = 76054528;                // 6144 f32
static constexpr size_t OFF_H1   = 76079104;                // 32768*2048 i8     = 67.1 MB
static constexpr size_t OFF_PART = 210296832;               // 32*32768 f32      = 4.2 MB

__device__ __forceinline__ void gl_lds16(const void* g, void* l) {
  __builtin_amdgcn_global_load_lds((const __attribute__((address_space(1))) u32*)g,
                                   (__attribute__((address_space(3))) u32*)l, 16, 0, 0);
}
__device__ __forceinline__ float sigm(float x) { return 1.f / (1.f + __expf(-x)); }
__device__ __forceinline__ float tanh_f(float x) {
  float e = __expf(-2.f * fabsf(x));
  float t = (1.f - e) / (1.f + e);
  return x < 0.f ? -t : t;
}

// ---------------- prep kernels ----------------

__global__ __launch_bounds__(256) void prep_e(const float* __restrict__ x,
                                              const float* __restrict__ pos,
                                              f16* __restrict__ e16) {
  int row = blockIdx.x;
  const float* xr = x + (size_t)row * 768;
  double ss = 0.0;
  for (int i = threadIdx.x; i < 768; i += 256) { float v = xr[i]; ss += (double)v * v; }
  __shared__ double red[256];
  red[threadIdx.x] = ss;
  __syncthreads();
  for (int s2 = 128; s2 > 0; s2 >>= 1) {
    if (threadIdx.x < s2) red[threadIdx.x] += red[threadIdx.x + s2];
    __syncthreads();
  }
  __shared__ int idx_s;
  if (threadIdx.x == 0) {
    int idx = (int)((float)sqrt(red[0]));
    idx_s = idx < 0 ? 0 : (idx > 127 ? 127 : idx);
  }
  __syncthreads();
  int idx = idx_s;
  for (int i = threadIdx.x; i < 1024; i += 256) {
    float v = (i < 768) ? xr[i] : pos[idx * 256 + (i - 768)];
    e16[(size_t)row * 1024 + i] = (f16)v;
  }
}

__global__ __launch_bounds__(256) void prep_w0(const float* __restrict__ w0f,
                                               const float* __restrict__ w0b,
                                               f16* __restrict__ w0p) {
  int t = blockIdx.x * 256 + threadIdx.x;
  int n = t >> 8;
  int k4 = (t & 255) * 4;
  int half = n >> 13;
  int nn = n & 8191;
  int d = nn >> 12;
  int r = nn & 4095;
  const float* w = d ? w0b : w0f;
  float4 v = *(const float4*)(w + (size_t)r * 2048 + half * 1024 + k4);
  f16x4 o;
  o[0] = (f16)v.x; o[1] = (f16)v.y; o[2] = (f16)v.z; o[3] = (f16)v.w;
  *(f16x4*)(w0p + (size_t)n * 1024 + k4) = o;
}

// W1q int8 [6144][2048], R3 packed-row layout: row n: ct=n/192 (d=ct>>4,
// h64=ct&15); r=n%192: wn=r/48, g=(r%48)>>4, hs=r&15; h=h64*64+wn*16+hs;
// gate gsel={i,c,o}[g]={0,2,3}[g].  Quant: round(w*4064), |w|<=1/32 -> |q|<=127.
__global__ __launch_bounds__(256) void prep_w1(const float* __restrict__ w1f,
                                               const float* __restrict__ w1b,
                                               signed char* __restrict__ w1q) {
  int t = blockIdx.x * 256 + threadIdx.x;   // 6144 blocks
  int n = t >> 8;                           // packed row 0..6143
  int c8 = (t & 255) * 8;
  int ct = n / 192, r = n % 192;
  int wn = r / 48, r2 = r % 48;
  int g = r2 >> 4, hs = r2 & 15;
  int d = ct >> 4;
  int h = (ct & 15) * 64 + wn * 16 + hs;
  int gsel = (g == 0) ? 0 : (g + 1);        // i, c, o
  const float* w = d ? w1b : w1f;
  const float* src = w + (size_t)(gsel * 1024 + h) * 2048 + c8;
  float4 v0 = *(const float4*)(src);
  float4 v1 = *(const float4*)(src + 4);
  c8x8 o;
  o[0] = (signed char)(int)rintf(v0.x * 4064.f);
  o[1] = (signed char)(int)rintf(v0.y * 4064.f);
  o[2] = (signed char)(int)rintf(v0.z * 4064.f);
  o[3] = (signed char)(int)rintf(v0.w * 4064.f);
  o[4] = (signed char)(int)rintf(v1.x * 4064.f);
  o[5] = (signed char)(int)rintf(v1.y * 4064.f);
  o[6] = (signed char)(int)rintf(v1.z * 4064.f);
  o[7] = (signed char)(int)rintf(v1.w * 4064.f);
  *(c8x8*)(w1q + (size_t)n * 2048 + c8) = o;
}

__global__ void prep_bias(const float* bi0f, const float* bh0f,
                          const float* bi0b, const float* bh0b,
                          const float* bi1f, const float* bh1f,
                          const float* bi1b, const float* bh1b,
                          float* bias0, float* bias1) {
  int i = blockIdx.x * 256 + threadIdx.x;
  if (i < 8192) {
    int d = i >> 12, r = i & 4095;
    bias0[i] = d ? (bi0b[r] + bh0b[r]) : (bi0f[r] + bh0f[r]);
  } else if (i < 8192 + 6144) {
    int n = i - 8192;
    int d = n / 3072, rem = n % 3072;
    int g3 = rem >> 10, k = rem & 1023;
    int gsel = (g3 == 0) ? 0 : (g3 + 1);
    int r = gsel * 1024 + k;
    bias1[n] = d ? (bi1b[r] + bh1b[r]) : (bi1f[r] + bh1f[r]);
  }
}

// ---------------- layer-0 GEMM: UV[256][16384] = e16 @ W0p.T ----------------
__global__ __launch_bounds__(256) void gemm_l0(const f16* __restrict__ e16,
                                               const f16* __restrict__ w0p,
                                               float* __restrict__ uv) {
  __shared__ __align__(16) f16 As[8192];
  __shared__ __align__(16) f16 Bs[8192];
  int n0 = blockIdx.x * 128;
  int m0 = blockIdx.y * 128;
  int tid = threadIdx.x, lane = tid & 63, w = tid >> 6;
  int wr = (w >> 1) * 64, wc = (w & 1) * 64;
  f32x4 acc[4][4] = {};

  for (int k0 = 0; k0 < 1024; k0 += 64) {
    __syncthreads();
#pragma unroll
    for (int q = 0; q < 4; q++) {
      int ch = tid + q * 256;
      int c = ch >> 7, r = ch & 127;
      gl_lds16(e16 + (size_t)(m0 + r) * 1024 + k0 + c * 8, (char*)As + ch * 16);
    }
#pragma unroll
    for (int q = 0; q < 4; q++) {
      int ch = tid + q * 256;
      int c = ch >> 7, r = ch & 127;
      gl_lds16(w0p + (size_t)(n0 + r) * 1024 + k0 + c * 8, (char*)Bs + ch * 16);
    }
    __syncthreads();
#pragma unroll
    for (int ks = 0; ks < 2; ks++) {
      int cb = ks * 4 + (lane >> 4);
      f16x8 a[4], b[4];
#pragma unroll
      for (int f = 0; f < 4; f++)
        a[f] = *(const f16x8*)(As + (cb * 128 + wr + f * 16 + (lane & 15)) * 8);
#pragma unroll
      for (int g = 0; g < 4; g++)
        b[g] = *(const f16x8*)(Bs + (cb * 128 + wc + g * 16 + (lane & 15)) * 8);
#pragma unroll
      for (int f = 0; f < 4; f++)
#pragma unroll
        for (int g = 0; g < 4; g++)
          acc[f][g] = __builtin_amdgcn_mfma_f32_16x16x32_f16(a[f], b[g], acc[f][g], 0, 0, 0);
    }
  }
  int col = lane & 15, lg = lane >> 4;
#pragma unroll
  for (int f = 0; f < 4; f++)
#pragma unroll
    for (int g = 0; g < 4; g++)
#pragma unroll
      for (int j = 0; j < 4; j++) {
        int row = m0 + wr + f * 16 + lg * 4 + j;
        int c = n0 + wc + g * 16 + col;
        uv[(size_t)row * 16384 + c] = acc[f][g][j];
      }
}

// ---------------- pair activation: h1 int8 [32768][2048] ----------------
__global__ __launch_bounds__(256) void pair_h1(const float* __restrict__ uv,
                                               const float* __restrict__ bias0,
                                               signed char* __restrict__ h1q) {
  int row = blockIdx.x;
  int urow = row >> 7;
  int b = row >> 14;
  int vrow = (b << 7) | (row & 127);
  int t = threadIdx.x;
  int u = t * 8;
  int d = u >> 10, k = u & 1023;
  const float* ub = uv + (size_t)urow * 16384 + d * 4096 + k;
  const float* vb = uv + (size_t)vrow * 16384 + 8192 + d * 4096 + k;
  const float* bb = bias0 + d * 4096 + k;
  f32x8 ui = *(const f32x8*)(ub);
  f32x8 uc = *(const f32x8*)(ub + 2048);
  f32x8 uo = *(const f32x8*)(ub + 3072);
  f32x8 vi = *(const f32x8*)(vb);
  f32x8 vc = *(const f32x8*)(vb + 2048);
  f32x8 vo = *(const f32x8*)(vb + 3072);
  f32x8 bi = *(const f32x8*)(bb);
  f32x8 bc = *(const f32x8*)(bb + 2048);
  f32x8 bo = *(const f32x8*)(bb + 3072);
  c8x8 ov;
#pragma unroll
  for (int e = 0; e < 8; e++) {
    float gi = ui[e] + vi[e] + bi[e];
    float gc = uc[e] + vc[e] + bc[e];
    float go = uo[e] + vo[e] + bo[e];
    float cell = sigm(gi) * tanh_f(gc);
    float hv = sigm(go) * tanh_f(cell);
    ov[e] = (signed char)(int)rintf(hv * 127.f);
  }
  *(c8x8*)(h1q + (size_t)row * 2048 + u) = ov;
}

// ---------------- fused layer-1 GEMM (int8) + LSTM cell + FC ----------------
// A-from-global variant: A fragments loaded straight from h1q (16 rows x 64 B
// contiguous sectors per instr; the 16 KB/tile A-panel is L1-resident and
// shared by all 4 waves). LDS holds ONLY B (3-deep rotation, 72 KB,
// 2 blocks/CU). One barrier per tile. Counted vmcnt: A-loads are issued
// BEFORE stage-B, so compiler waits for A keep the 6 B-DMAs in flight;
// explicit vmcnt(6) at tile end proves B(t+1) landed (B(t+2)=6 newest ops).
// Race: buf (t+2)%3 written in tile t was last read tile t-1, drained at that
// barrier. B LDS addressing = R3/R7 verified 0-conflict pattern.
__global__ __launch_bounds__(256, 2) void gemm_l1(const signed char* __restrict__ h1q,
                                                  const signed char* __restrict__ w1q,
                                                  const float* __restrict__ bias1,
                                                  const float* __restrict__ fcw,
                                                  float* __restrict__ partial) {
  __shared__ __align__(16) signed char Bs[3][24576];   // [buf] 192 rows x 128B
  int ct = blockIdx.x;                  // 0..31  (d = ct>>4, h-block = ct&15)
  int m0 = blockIdx.y * 128;
  int d = ct >> 4;
  int tid = threadIdx.x, lane = tid & 63;
  int wn = tid >> 6;                    // wave: all 128 rows, cols [wn*48,+48)
  int la = lane & 15, lq = lane >> 4, l8 = lane & 7;

  // B staging: LDS chunk ch = pr*8+slot holds source 16B-chunk c = slot^(pr&7)
  const signed char* bsrc[6]; signed char* bdst[6];
#pragma unroll
  for (int q = 0; q < 6; q++) {
    int ch = tid + q * 256, pr = ch >> 3, slot = ch & 7, c = slot ^ (pr & 7);
    bsrc[q] = w1q + (size_t)(ct * 192 + pr) * 2048 + c * 16;
    bdst[q] = &Bs[0][ch * 16];
  }
  auto stageB = [&](int t, int sb) {
#pragma unroll
    for (int q = 0; q < 6; q++) gl_lds16(bsrc[q] + t * 128, bdst[q] + sb * 24576);
  };

  // A global base: row = m0 + rf*16 + la, k-chunk = ks*4+lq within 128B tile slice
  const signed char* abase = h1q + (size_t)(m0 + la) * 2048 + lq * 16;

  i32x4 acc[8][3] = {};
  stageB(0, 0);
  stageB(1, 1);
  asm volatile("s_waitcnt vmcnt(0)" ::: "memory");
  __builtin_amdgcn_s_barrier();

  for (int t = 0; t < 16; ++t) {
    int buf = t % 3;
    int sb = buf + 2; if (sb >= 3) sb -= 3;            // (t+2)%3
    const signed char* Bb = &Bs[buf][0];
    // ---- A fragments from global (issued first: oldest in vmcnt order) ----
    i32x4 af[2][8];
#pragma unroll
    for (int ks = 0; ks < 2; ks++)
#pragma unroll
      for (int rf = 0; rf < 8; rf++)
        af[ks][rf] = *(const i32x4*)(abase + (size_t)rf * 32768 + t * 128 + ks * 64);
    // ---- stage B(t+2) (newest 6 vmem ops) ----
    if (t < 14) stageB(t + 2, sb);
    // ---- B fragments from LDS ----
    i32x4 bf[2][3];
#pragma unroll
    for (int ks = 0; ks < 2; ks++) {
      int slot = (ks * 4 + lq) ^ l8;
#pragma unroll
      for (int cf = 0; cf < 3; cf++)
        bf[ks][cf] = *(const i32x4*)(Bb + ((wn * 48 + cf * 16 + la) * 8 + slot) * 16);
    }
    // ---- MFMAs (compiler inserts counted vmcnt/lgkm waits for af/bf) ----
    __builtin_amdgcn_s_setprio(1);
#pragma unroll
    for (int ks = 0; ks < 2; ks++)
#pragma unroll
      for (int rf = 0; rf < 8; rf++)
#pragma unroll
        for (int cf = 0; cf < 3; cf++)
          acc[rf][cf] = __builtin_amdgcn_mfma_i32_16x16x64_i8(
              af[ks][rf], bf[ks][cf], acc[rf][cf], 0, 0, 0);
    __builtin_amdgcn_s_setprio(0);
    // ---- publish: B(t+1) landed (only B(t+2)'s 6 ops may remain in flight) ----
    if (t < 14)      { asm volatile("s_waitcnt vmcnt(6)" ::: "memory"); }
    else             { asm volatile("s_waitcnt vmcnt(0)" ::: "memory"); }
    __builtin_amdgcn_sched_barrier(0);
    __builtin_amdgcn_s_barrier();
  }

  // epilogue: dequant + LSTM cell + fc dot; reduce 16 lanes (h) then cross-wn
  // via LDS (sred aliases Bs[0]; all LDS reads retired before final barrier).
  float* sred = (float*)&Bs[0][0];      // 4*128 floats = 2 KB
  const float S = 1.0f / 516128.0f;     // 1/(127*4064)
  int hcol = (ct & 15) * 64 + wn * 16 + la;
  float bi = bias1[(d * 3 + 0) * 1024 + hcol];
  float bc = bias1[(d * 3 + 1) * 1024 + hcol];
  float bo = bias1[(d * 3 + 2) * 1024 + hcol];
  float wf = fcw[d * 1024 + hcol];
#pragma unroll
  for (int rf = 0; rf < 8; rf++) {
#pragma unroll
    for (int j = 0; j < 4; j++) {
      float gi = (float)acc[rf][0][j] * S + bi;
      float gc = (float)acc[rf][1][j] * S + bc;
      float go = (float)acc[rf][2][j] * S + bo;
      float cell = sigm(gi) * tanh_f(gc);
      float hv = sigm(go) * tanh_f(cell);
      float v = hv * wf;
      v += __shfl_xor(v, 1);
      v += __shfl_xor(v, 2);
      v += __shfl_xor(v, 4);
      v += __shfl_xor(v, 8);
      if (la == 0) sred[wn * 128 + rf * 16 + lq * 4 + j] = v;
    }
  }
  __syncthreads();
  if (tid < 128) {
    float s = sred[tid] + sred[128 + tid] + sred[256 + tid] + sred[384 + tid];
    partial[(size_t)ct * 32768 + m0 + tid] = s;
  }
}

__global__ void reduce_out(const float* __restrict__ partial,
                           const float* __restrict__ fcb,
                           float* __restrict__ out) {
  int m = blockIdx.x * 256 + threadIdx.x;
  float s = fcb[0];
#pragma unroll
  for (int ct = 0; ct < 32; ct++) s += partial[(size_t)ct * 32768 + m];
  out[m] = s;
}

// ---------------- launch ----------------
extern "C" void kernel_launch(void* const* d_in, const int* in_sizes, int n_in,
                              void* d_out, int out_size, void* d_ws, size_t ws_size,
                              hipStream_t stream) {
  const float* x    = (const float*)d_in[0];
  const float* pos  = (const float*)d_in[1];
  const float* w0f  = (const float*)d_in[2];
  const float* bi0f = (const float*)d_in[3];
  const float* bh0f = (const float*)d_in[4];
  const float* w0b  = (const float*)d_in[5];
  const float* bi0b = (const float*)d_in[6];
  const float* bh0b = (const float*)d_in[7];
  const float* w1f  = (const float*)d_in[8];
  const float* bi1f = (const float*)d_in[9];
  const float* bh1f = (const float*)d_in[10];
  const float* w1b  = (const float*)d_in[11];
  const float* bi1b = (const float*)d_in[12];
  const float* bh1b = (const float*)d_in[13];
  const float* fcw  = (const float*)d_in[14];
  const float* fcb  = (const float*)d_in[15];
  float* out = (float*)d_out;

  char* ws = (char*)d_ws;
  f16*   e16   = (f16*)(ws + OFF_E16);
  f16*   w0p   = (f16*)(ws + OFF_W0P);
  float* uv    = (float*)(ws + OFF_UV);
  float* bias0 = (float*)(ws + OFF_B0);
  signed char* w1q = (signed char*)(ws + OFF_W1P);
  float* bias1 = (float*)(ws + OFF_B1);
  signed char* h1q = (signed char*)(ws + OFF_H1);
  float* part  = (float*)(ws + OFF_PART);

  prep_e<<<256, 256, 0, stream>>>(x, pos, e16);
  prep_w0<<<16384, 256, 0, stream>>>(w0f, w0b, w0p);
  prep_w1<<<6144, 256, 0, stream>>>(w1f, w1b, w1q);
  prep_bias<<<56, 256, 0, stream>>>(bi0f, bh0f, bi0b, bh0b, bi1f, bh1f, bi1b, bh1b,
                                    bias0, bias1);
  gemm_l0<<<dim3(128, 2), 256, 0, stream>>>(e16, w0p, uv);
  pair_h1<<<32768, 256, 0, stream>>>(uv, bias0, h1q);
  gemm_l1<<<dim3(32, 256), 256, 0, stream>>>(h1q, w1q, bias1, fcw, part);
  reduce_out<<<128, 256, 0, stream>>>(part, fcb, out);
}

// Round 10
// 696.428 us; speedup vs baseline: 1.9562x; 1.9562x over previous
//
#include <hip/hip_runtime.h>
#include <cstdint>

typedef _Float16 f16;
typedef f16   f16x8 __attribute__((ext_vector_type(8)));
typedef f16   f16x4 __attribute__((ext_vector_type(4)));
typedef float f32x4 __attribute__((ext_vector_type(4)));
typedef float f32x8 __attribute__((ext_vector_type(8)));
typedef int   i32x4 __attribute__((ext_vector_type(4)));
typedef signed char c8x8 __attribute__((ext_vector_type(8)));
typedef unsigned int u32;

// Problem dims: B=2, S=128, DIN=768, PPOS=256, DCAT=2048, H=1024
// N_pairs = 32768, e rows = 256.

// workspace layout (bytes)
static constexpr size_t OFF_E16  = 0;                       // 256*1024 f16      = 0.5 MB
static constexpr size_t OFF_W0P  = 524288;                  // 16384*1024 f16    = 33.5 MB
static constexpr size_t OFF_UV   = 34078720;                // 256*16384 f32     = 16.8 MB
static constexpr size_t OFF_B0   = 50855936;                // 8192 f32
static constexpr size_t OFF_W1P  = 50888704;                // 6144*2048 i8      = 12.6 MB
static constexpr size_t OFF_B1   = 76054528;                // 6144 f32
static constexpr size_t OFF_H1   = 76079104;                // 32768*2048 i8     = 67.1 MB
static constexpr size_t OFF_PART = 210296832;               // 32*32768 f32      = 4.2 MB

__device__ __forceinline__ void gl_lds16(const void* g, void* l) {
  __builtin_amdgcn_global_load_lds((const __attribute__((address_space(1))) u32*)g,
                                   (__attribute__((address_space(3))) u32*)l, 16, 0, 0);
}
__device__ __forceinline__ float sigm(float x) { return 1.f / (1.f + __expf(-x)); }
__device__ __forceinline__ float tanh_f(float x) {
  float e = __expf(-2.f * fabsf(x));
  float t = (1.f - e) / (1.f + e);
  return x < 0.f ? -t : t;
}

// ---------------- prep kernels ----------------

__global__ __launch_bounds__(256) void prep_e(const float* __restrict__ x,
                                              const float* __restrict__ pos,
                                              f16* __restrict__ e16) {
  int row = blockIdx.x;
  const float* xr = x + (size_t)row * 768;
  double ss = 0.0;
  for (int i = threadIdx.x; i < 768; i += 256) { float v = xr[i]; ss += (double)v * v; }
  __shared__ double red[256];
  red[threadIdx.x] = ss;
  __syncthreads();
  for (int s2 = 128; s2 > 0; s2 >>= 1) {
    if (threadIdx.x < s2) red[threadIdx.x] += red[threadIdx.x + s2];
    __syncthreads();
  }
  __shared__ int idx_s;
  if (threadIdx.x == 0) {
    int idx = (int)((float)sqrt(red[0]));
    idx_s = idx < 0 ? 0 : (idx > 127 ? 127 : idx);
  }
  __syncthreads();
  int idx = idx_s;
  for (int i = threadIdx.x; i < 1024; i += 256) {
    float v = (i < 768) ? xr[i] : pos[idx * 256 + (i - 768)];
    e16[(size_t)row * 1024 + i] = (f16)v;
  }
}

__global__ __launch_bounds__(256) void prep_w0(const float* __restrict__ w0f,
                                               const float* __restrict__ w0b,
                                               f16* __restrict__ w0p) {
  int t = blockIdx.x * 256 + threadIdx.x;
  int n = t >> 8;
  int k4 = (t & 255) * 4;
  int half = n >> 13;
  int nn = n & 8191;
  int d = nn >> 12;
  int r = nn & 4095;
  const float* w = d ? w0b : w0f;
  float4 v = *(const float4*)(w + (size_t)r * 2048 + half * 1024 + k4);
  f16x4 o;
  o[0] = (f16)v.x; o[1] = (f16)v.y; o[2] = (f16)v.z; o[3] = (f16)v.w;
  *(f16x4*)(w0p + (size_t)n * 1024 + k4) = o;
}

// W1q int8 [6144][2048], R3 packed-row layout: row n: ct=n/192 (d=ct>>4,
// h64=ct&15); r=n%192: wn=r/48, g=(r%48)>>4, hs=r&15; h=h64*64+wn*16+hs;
// gate gsel={i,c,o}[g]={0,2,3}[g].  Quant: round(w*4064), |w|<=1/32 -> |q|<=127.
__global__ __launch_bounds__(256) void prep_w1(const float* __restrict__ w1f,
                                               const float* __restrict__ w1b,
                                               signed char* __restrict__ w1q) {
  int t = blockIdx.x * 256 + threadIdx.x;   // 6144 blocks
  int n = t >> 8;                           // packed row 0..6143
  int c8 = (t & 255) * 8;
  int ct = n / 192, r = n % 192;
  int wn = r / 48, r2 = r % 48;
  int g = r2 >> 4, hs = r2 & 15;
  int d = ct >> 4;
  int h = (ct & 15) * 64 + wn * 16 + hs;
  int gsel = (g == 0) ? 0 : (g + 1);        // i, c, o
  const float* w = d ? w1b : w1f;
  const float* src = w + (size_t)(gsel * 1024 + h) * 2048 + c8;
  float4 v0 = *(const float4*)(src);
  float4 v1 = *(const float4*)(src + 4);
  c8x8 o;
  o[0] = (signed char)(int)rintf(v0.x * 4064.f);
  o[1] = (signed char)(int)rintf(v0.y * 4064.f);
  o[2] = (signed char)(int)rintf(v0.z * 4064.f);
  o[3] = (signed char)(int)rintf(v0.w * 4064.f);
  o[4] = (signed char)(int)rintf(v1.x * 4064.f);
  o[5] = (signed char)(int)rintf(v1.y * 4064.f);
  o[6] = (signed char)(int)rintf(v1.z * 4064.f);
  o[7] = (signed char)(int)rintf(v1.w * 4064.f);
  *(c8x8*)(w1q + (size_t)n * 2048 + c8) = o;
}

__global__ void prep_bias(const float* bi0f, const float* bh0f,
                          const float* bi0b, const float* bh0b,
                          const float* bi1f, const float* bh1f,
                          const float* bi1b, const float* bh1b,
                          float* bias0, float* bias1) {
  int i = blockIdx.x * 256 + threadIdx.x;
  if (i < 8192) {
    int d = i >> 12, r = i & 4095;
    bias0[i] = d ? (bi0b[r] + bh0b[r]) : (bi0f[r] + bh0f[r]);
  } else if (i < 8192 + 6144) {
    int n = i - 8192;
    int d = n / 3072, rem = n % 3072;
    int g3 = rem >> 10, k = rem & 1023;
    int gsel = (g3 == 0) ? 0 : (g3 + 1);
    int r = gsel * 1024 + k;
    bias1[n] = d ? (bi1b[r] + bh1b[r]) : (bi1f[r] + bh1f[r]);
  }
}

// ---------------- layer-0 GEMM: UV[256][16384] = e16 @ W0p.T ----------------
__global__ __launch_bounds__(256) void gemm_l0(const f16* __restrict__ e16,
                                               const f16* __restrict__ w0p,
                                               float* __restrict__ uv) {
  __shared__ __align__(16) f16 As[8192];
  __shared__ __align__(16) f16 Bs[8192];
  int n0 = blockIdx.x * 128;
  int m0 = blockIdx.y * 128;
  int tid = threadIdx.x, lane = tid & 63, w = tid >> 6;
  int wr = (w >> 1) * 64, wc = (w & 1) * 64;
  f32x4 acc[4][4] = {};

  for (int k0 = 0; k0 < 1024; k0 += 64) {
    __syncthreads();
#pragma unroll
    for (int q = 0; q < 4; q++) {
      int ch = tid + q * 256;
      int c = ch >> 7, r = ch & 127;
      gl_lds16(e16 + (size_t)(m0 + r) * 1024 + k0 + c * 8, (char*)As + ch * 16);
    }
#pragma unroll
    for (int q = 0; q < 4; q++) {
      int ch = tid + q * 256;
      int c = ch >> 7, r = ch & 127;
      gl_lds16(w0p + (size_t)(n0 + r) * 1024 + k0 + c * 8, (char*)Bs + ch * 16);
    }
    __syncthreads();
#pragma unroll
    for (int ks = 0; ks < 2; ks++) {
      int cb = ks * 4 + (lane >> 4);
      f16x8 a[4], b[4];
#pragma unroll
      for (int f = 0; f < 4; f++)
        a[f] = *(const f16x8*)(As + (cb * 128 + wr + f * 16 + (lane & 15)) * 8);
#pragma unroll
      for (int g = 0; g < 4; g++)
        b[g] = *(const f16x8*)(Bs + (cb * 128 + wc + g * 16 + (lane & 15)) * 8);
#pragma unroll
      for (int f = 0; f < 4; f++)
#pragma unroll
        for (int g = 0; g < 4; g++)
          acc[f][g] = __builtin_amdgcn_mfma_f32_16x16x32_f16(a[f], b[g], acc[f][g], 0, 0, 0);
    }
  }
  int col = lane & 15, lg = lane >> 4;
#pragma unroll
  for (int f = 0; f < 4; f++)
#pragma unroll
    for (int g = 0; g < 4; g++)
#pragma unroll
      for (int j = 0; j < 4; j++) {
        int row = m0 + wr + f * 16 + lg * 4 + j;
        int c = n0 + wc + g * 16 + col;
        uv[(size_t)row * 16384 + c] = acc[f][g][j];
      }
}

// ---------------- pair activation: h1 int8 [32768][2048] ----------------
__global__ __launch_bounds__(256) void pair_h1(const float* __restrict__ uv,
                                               const float* __restrict__ bias0,
                                               signed char* __restrict__ h1q) {
  int row = blockIdx.x;
  int urow = row >> 7;
  int b = row >> 14;
  int vrow = (b << 7) | (row & 127);
  int t = threadIdx.x;
  int u = t * 8;
  int d = u >> 10, k = u & 1023;
  const float* ub = uv + (size_t)urow * 16384 + d * 4096 + k;
  const float* vb = uv + (size_t)vrow * 16384 + 8192 + d * 4096 + k;
  const float* bb = bias0 + d * 4096 + k;
  f32x8 ui = *(const f32x8*)(ub);
  f32x8 uc = *(const f32x8*)(ub + 2048);
  f32x8 uo = *(const f32x8*)(ub + 3072);
  f32x8 vi = *(const f32x8*)(vb);
  f32x8 vc = *(const f32x8*)(vb + 2048);
  f32x8 vo = *(const f32x8*)(vb + 3072);
  f32x8 bi = *(const f32x8*)(bb);
  f32x8 bc = *(const f32x8*)(bb + 2048);
  f32x8 bo = *(const f32x8*)(bb + 3072);
  c8x8 ov;
#pragma unroll
  for (int e = 0; e < 8; e++) {
    float gi = ui[e] + vi[e] + bi[e];
    float gc = uc[e] + vc[e] + bc[e];
    float go = uo[e] + vo[e] + bo[e];
    float cell = sigm(gi) * tanh_f(gc);
    float hv = sigm(go) * tanh_f(cell);
    ov[e] = (signed char)(int)rintf(hv * 127.f);
  }
  *(c8x8*)(h1q + (size_t)row * 2048 + u) = ov;
}

// ---------------- fused layer-1 GEMM (int8) + LSTM cell + FC ----------------
// Single-barrier pipeline: block 256 rows x 192 cols, 512 thr / 8 waves
// (2M x 4N, wave tile 128x48 = R7 wave geometry & R7 0-conflict addressing).
// BK=128B. A double-buffered (stage 1 tile ahead), B triple-buffered (stage
// 2 tiles ahead); 136 KB LDS, 1 block/CU. Per tile: 22 ds_reads -> issue
// stageA(t+1)[4] + stageB(t+2)[3] (both into buffers NOT referenced this
// tile -> no mid-tile drain) -> 48 MFMA (compiler lgkm-interleaves) ->
// vmcnt(3) (A(t+1)+B(t+1) landed; B(t+2) stays in flight) -> one barrier.
// Races: every buffer written in tile t was last read in tile t-1, and those
// reads retired before the t-1 barrier (MFMAs consumed them).
__global__ __launch_bounds__(512, 1) void gemm_l1(const signed char* __restrict__ h1q,
                                                  const signed char* __restrict__ w1q,
                                                  const float* __restrict__ bias1,
                                                  const float* __restrict__ fcw,
                                                  float* __restrict__ partial) {
  __shared__ __align__(16) signed char As[2][32768];   // 256 rows x 128B per buf
  __shared__ __align__(16) signed char Bs[3][24576];   // 192 rows x 128B per buf
  int ct = blockIdx.x;                  // 0..31  (d = ct>>4, h-block = ct&15)
  int m0 = blockIdx.y * 256;
  int d = ct >> 4;
  int tid = threadIdx.x, lane = tid & 63, w = tid >> 6;
  int wm = w >> 2, wn = w & 3;          // wave: rows [wm*128,+128) cols [wn*48,+48)
  int la = lane & 15, lq = lane >> 4, l8 = lane & 7;

  // staging: LDS chunk ch = r*8+slot holds source 16B-chunk c = slot^(r&7)
  const signed char* asrc[4]; signed char* adst[4];
#pragma unroll
  for (int q = 0; q < 4; q++) {
    int ch = tid + q * 512, r = ch >> 3, slot = ch & 7, c = slot ^ (r & 7);
    asrc[q] = h1q + (size_t)(m0 + r) * 2048 + c * 16;
    adst[q] = &As[0][ch * 16];
  }
  const signed char* bsrc[3]; signed char* bdst[3];
#pragma unroll
  for (int q = 0; q < 3; q++) {
    int ch = tid + q * 512, pr = ch >> 3, slot = ch & 7, c = slot ^ (pr & 7);
    bsrc[q] = w1q + (size_t)(ct * 192 + pr) * 2048 + c * 16;
    bdst[q] = &Bs[0][ch * 16];
  }
  auto stageA = [&](int t, int ab) {
#pragma unroll
    for (int q = 0; q < 4; q++) gl_lds16(asrc[q] + t * 128, adst[q] + ab * 32768);
  };
  auto stageB = [&](int t, int bb) {
#pragma unroll
    for (int q = 0; q < 3; q++) gl_lds16(bsrc[q] + t * 128, bdst[q] + bb * 24576);
  };

  i32x4 acc[8][3] = {};
  stageA(0, 0); stageB(0, 0); stageB(1, 1);
  asm volatile("s_waitcnt vmcnt(3)" ::: "memory");   // A(0)+B(0) landed
  __builtin_amdgcn_s_barrier();

  for (int t = 0; t < 16; ++t) {
    int ab = t & 1;
    int bb = t % 3;
    const signed char* Ab = &As[ab][0];
    const signed char* Bb = &Bs[bb][0];
    // ---- fragment reads (R7 0-conflict pattern) ----
    i32x4 af[2][8], bf[2][3];
#pragma unroll
    for (int ks = 0; ks < 2; ks++) {
      int slot = (ks * 4 + lq) ^ l8;
#pragma unroll
      for (int rf = 0; rf < 8; rf++) {
        int R = wm * 128 + rf * 16 + la;
        af[ks][rf] = *(const i32x4*)(Ab + (R * 8 + slot) * 16);
      }
#pragma unroll
      for (int cf = 0; cf < 3; cf++) {
        int P = wn * 48 + cf * 16 + la;
        bf[ks][cf] = *(const i32x4*)(Bb + (P * 8 + slot) * 16);
      }
    }
    // ---- prefetch stages (targets not referenced this tile) ----
    if (t < 15) stageA(t + 1, (t + 1) & 1);
    if (t < 14) stageB(t + 2, (t + 2) % 3);
    // ---- MFMAs (compiler interleaves with the in-flight ds_reads) ----
    __builtin_amdgcn_s_setprio(1);
#pragma unroll
    for (int ks = 0; ks < 2; ks++)
#pragma unroll
      for (int rf = 0; rf < 8; rf++)
#pragma unroll
        for (int cf = 0; cf < 3; cf++)
          acc[rf][cf] = __builtin_amdgcn_mfma_i32_16x16x64_i8(
              af[ks][rf], bf[ks][cf], acc[rf][cf], 0, 0, 0);
    __builtin_amdgcn_s_setprio(0);
    // ---- publish: A(t+1)+B(t+1) landed; B(t+2) stays in flight ----
    if (t < 14)      { asm volatile("s_waitcnt vmcnt(3)" ::: "memory"); }
    else             { asm volatile("s_waitcnt vmcnt(0)" ::: "memory"); }
    __builtin_amdgcn_sched_barrier(0);
    __builtin_amdgcn_s_barrier();
  }

  // epilogue: dequant + LSTM cell + fc dot; reduce 16 lanes (h) then cross-wn
  // via LDS (sred aliases Bs[0]; all LDS reads retired before final barrier).
  float* sred = (float*)&Bs[0][0];      // 4*256 floats = 4 KB
  const float S = 1.0f / 516128.0f;     // 1/(127*4064)
  int hcol = (ct & 15) * 64 + wn * 16 + la;
  float bi = bias1[(d * 3 + 0) * 1024 + hcol];
  float bc = bias1[(d * 3 + 1) * 1024 + hcol];
  float bo = bias1[(d * 3 + 2) * 1024 + hcol];
  float wf = fcw[d * 1024 + hcol];
#pragma unroll
  for (int rf = 0; rf < 8; rf++) {
#pragma unroll
    for (int j = 0; j < 4; j++) {
      float gi = (float)acc[rf][0][j] * S + bi;
      float gc = (float)acc[rf][1][j] * S + bc;
      float go = (float)acc[rf][2][j] * S + bo;
      float cell = sigm(gi) * tanh_f(gc);
      float hv = sigm(go) * tanh_f(cell);
      float v = hv * wf;
      v += __shfl_xor(v, 1);
      v += __shfl_xor(v, 2);
      v += __shfl_xor(v, 4);
      v += __shfl_xor(v, 8);
      if (la == 0) sred[wn * 256 + wm * 128 + rf * 16 + lq * 4 + j] = v;
    }
  }
  __syncthreads();
  if (tid < 256) {
    float s = sred[tid] + sred[256 + tid] + sred[512 + tid] + sred[768 + tid];
    partial[(size_t)ct * 32768 + m0 + tid] = s;
  }
}

__global__ void reduce_out(const float* __restrict__ partial,
                           const float* __restrict__ fcb,
                           float* __restrict__ out) {
  int m = blockIdx.x * 256 + threadIdx.x;
  float s = fcb[0];
#pragma unroll
  for (int ct = 0; ct < 32; ct++) s += partial[(size_t)ct * 32768 + m];
  out[m] = s;
}

// ---------------- launch ----------------
extern "C" void kernel_launch(void* const* d_in, const int* in_sizes, int n_in,
                              void* d_out, int out_size, void* d_ws, size_t ws_size,
                              hipStream_t stream) {
  const float* x    = (const float*)d_in[0];
  const float* pos  = (const float*)d_in[1];
  const float* w0f  = (const float*)d_in[2];
  const float* bi0f = (const float*)d_in[3];
  const float* bh0f = (const float*)d_in[4];
  const float* w0b  = (const float*)d_in[5];
  const float* bi0b = (const float*)d_in[6];
  const float* bh0b = (const float*)d_in[7];
  const float* w1f  = (const float*)d_in[8];
  const float* bi1f = (const float*)d_in[9];
  const float* bh1f = (const float*)d_in[10];
  const float* w1b  = (const float*)d_in[11];
  const float* bi1b = (const float*)d_in[12];
  const float* bh1b = (const float*)d_in[13];
  const float* fcw  = (const float*)d_in[14];
  const float* fcb  = (const float*)d_in[15];
  float* out = (float*)d_out;

  char* ws = (char*)d_ws;
  f16*   e16   = (f16*)(ws + OFF_E16);
  f16*   w0p   = (f16*)(ws + OFF_W0P);
  float* uv    = (float*)(ws + OFF_UV);
  float* bias0 = (float*)(ws + OFF_B0);
  signed char* w1q = (signed char*)(ws + OFF_W1P);
  float* bias1 = (float*)(ws + OFF_B1);
  signed char* h1q = (signed char*)(ws + OFF_H1);
  float* part  = (float*)(ws + OFF_PART);

  prep_e<<<256, 256, 0, stream>>>(x, pos, e16);
  prep_w0<<<16384, 256, 0, stream>>>(w0f, w0b, w0p);
  prep_w1<<<6144, 256, 0, stream>>>(w1f, w1b, w1q);
  prep_bias<<<56, 256, 0, stream>>>(bi0f, bh0f, bi0b, bh0b, bi1f, bh1f, bi1b, bh1b,
                                    bias0, bias1);
  gemm_l0<<<dim3(128, 2), 256, 0, stream>>>(e16, w0p, uv);
  pair_h1<<<32768, 256, 0, stream>>>(uv, bias0, h1q);
  gemm_l1<<<dim3(32, 128), 512, 0, stream>>>(h1q, w1q, bias1, fcw, part);
  reduce_out<<<128, 256, 0, stream>>>(part, fcb, out);
}

// Round 11
// 686.817 us; speedup vs baseline: 1.9836x; 1.0140x over previous
//
#include <hip/hip_runtime.h>
#include <cstdint>

typedef _Float16 f16;
typedef f16   f16x8 __attribute__((ext_vector_type(8)));
typedef f16   f16x4 __attribute__((ext_vector_type(4)));
typedef float f32x4 __attribute__((ext_vector_type(4)));
typedef float f32x8 __attribute__((ext_vector_type(8)));
typedef int   i32x4 __attribute__((ext_vector_type(4)));
typedef signed char c8x8 __attribute__((ext_vector_type(8)));
typedef unsigned int u32;

// Problem dims: B=2, S=128, DIN=768, PPOS=256, DCAT=2048, H=1024
// N_pairs = 32768, e rows = 256.

// workspace layout (bytes)
static constexpr size_t OFF_E16  = 0;                       // 256*1024 f16      = 0.5 MB
static constexpr size_t OFF_W0P  = 524288;                  // 16384*1024 f16    = 33.5 MB
static constexpr size_t OFF_UV   = 34078720;                // 256*16384 f32     = 16.8 MB
static constexpr size_t OFF_B0   = 50855936;                // 8192 f32
static constexpr size_t OFF_W1P  = 50888704;                // 6144*2048 i8      = 12.6 MB
static constexpr size_t OFF_B1   = 76054528;                // 6144 f32
static constexpr size_t OFF_H1   = 76079104;                // 32768*2048 i8     = 67.1 MB
static constexpr size_t OFF_PART = 210296832;               // 32*32768 f32      = 4.2 MB

__device__ __forceinline__ void gl_lds16(const void* g, void* l) {
  __builtin_amdgcn_global_load_lds((const __attribute__((address_space(1))) u32*)g,
                                   (__attribute__((address_space(3))) u32*)l, 16, 0, 0);
}
__device__ __forceinline__ float sigm(float x) { return 1.f / (1.f + __expf(-x)); }
__device__ __forceinline__ float tanh_f(float x) {
  float e = __expf(-2.f * fabsf(x));
  float t = (1.f - e) / (1.f + e);
  return x < 0.f ? -t : t;
}

// ---------------- prep kernels ----------------

__global__ __launch_bounds__(256) void prep_e(const float* __restrict__ x,
                                              const float* __restrict__ pos,
                                              f16* __restrict__ e16) {
  int row = blockIdx.x;
  const float* xr = x + (size_t)row * 768;
  double ss = 0.0;
  for (int i = threadIdx.x; i < 768; i += 256) { float v = xr[i]; ss += (double)v * v; }
  __shared__ double red[256];
  red[threadIdx.x] = ss;
  __syncthreads();
  for (int s2 = 128; s2 > 0; s2 >>= 1) {
    if (threadIdx.x < s2) red[threadIdx.x] += red[threadIdx.x + s2];
    __syncthreads();
  }
  __shared__ int idx_s;
  if (threadIdx.x == 0) {
    int idx = (int)((float)sqrt(red[0]));
    idx_s = idx < 0 ? 0 : (idx > 127 ? 127 : idx);
  }
  __syncthreads();
  int idx = idx_s;
  for (int i = threadIdx.x; i < 1024; i += 256) {
    float v = (i < 768) ? xr[i] : pos[idx * 256 + (i - 768)];
    e16[(size_t)row * 1024 + i] = (f16)v;
  }
}

__global__ __launch_bounds__(256) void prep_w0(const float* __restrict__ w0f,
                                               const float* __restrict__ w0b,
                                               f16* __restrict__ w0p) {
  int t = blockIdx.x * 256 + threadIdx.x;
  int n = t >> 8;
  int k4 = (t & 255) * 4;
  int half = n >> 13;
  int nn = n & 8191;
  int d = nn >> 12;
  int r = nn & 4095;
  const float* w = d ? w0b : w0f;
  float4 v = *(const float4*)(w + (size_t)r * 2048 + half * 1024 + k4);
  f16x4 o;
  o[0] = (f16)v.x; o[1] = (f16)v.y; o[2] = (f16)v.z; o[3] = (f16)v.w;
  *(f16x4*)(w0p + (size_t)n * 1024 + k4) = o;
}

// W1q int8 [6144][2048], R3 packed-row layout: row n: ct=n/192 (d=ct>>4,
// h64=ct&15); r=n%192: wn=r/48, g=(r%48)>>4, hs=r&15; h=h64*64+wn*16+hs;
// gate gsel={i,c,o}[g]={0,2,3}[g].  Quant: round(w*4064), |w|<=1/32 -> |q|<=127.
__global__ __launch_bounds__(256) void prep_w1(const float* __restrict__ w1f,
                                               const float* __restrict__ w1b,
                                               signed char* __restrict__ w1q) {
  int t = blockIdx.x * 256 + threadIdx.x;   // 6144 blocks
  int n = t >> 8;                           // packed row 0..6143
  int c8 = (t & 255) * 8;
  int ct = n / 192, r = n % 192;
  int wn = r / 48, r2 = r % 48;
  int g = r2 >> 4, hs = r2 & 15;
  int d = ct >> 4;
  int h = (ct & 15) * 64 + wn * 16 + hs;
  int gsel = (g == 0) ? 0 : (g + 1);        // i, c, o
  const float* w = d ? w1b : w1f;
  const float* src = w + (size_t)(gsel * 1024 + h) * 2048 + c8;
  float4 v0 = *(const float4*)(src);
  float4 v1 = *(const float4*)(src + 4);
  c8x8 o;
  o[0] = (signed char)(int)rintf(v0.x * 4064.f);
  o[1] = (signed char)(int)rintf(v0.y * 4064.f);
  o[2] = (signed char)(int)rintf(v0.z * 4064.f);
  o[3] = (signed char)(int)rintf(v0.w * 4064.f);
  o[4] = (signed char)(int)rintf(v1.x * 4064.f);
  o[5] = (signed char)(int)rintf(v1.y * 4064.f);
  o[6] = (signed char)(int)rintf(v1.z * 4064.f);
  o[7] = (signed char)(int)rintf(v1.w * 4064.f);
  *(c8x8*)(w1q + (size_t)n * 2048 + c8) = o;
}

__global__ void prep_bias(const float* bi0f, const float* bh0f,
                          const float* bi0b, const float* bh0b,
                          const float* bi1f, const float* bh1f,
                          const float* bi1b, const float* bh1b,
                          float* bias0, float* bias1) {
  int i = blockIdx.x * 256 + threadIdx.x;
  if (i < 8192) {
    int d = i >> 12, r = i & 4095;
    bias0[i] = d ? (bi0b[r] + bh0b[r]) : (bi0f[r] + bh0f[r]);
  } else if (i < 8192 + 6144) {
    int n = i - 8192;
    int d = n / 3072, rem = n % 3072;
    int g3 = rem >> 10, k = rem & 1023;
    int gsel = (g3 == 0) ? 0 : (g3 + 1);
    int r = gsel * 1024 + k;
    bias1[n] = d ? (bi1b[r] + bh1b[r]) : (bi1f[r] + bh1f[r]);
  }
}

// ---------------- layer-0 GEMM: UV[256][16384] = e16 @ W0p.T ----------------
__global__ __launch_bounds__(256) void gemm_l0(const f16* __restrict__ e16,
                                               const f16* __restrict__ w0p,
                                               float* __restrict__ uv) {
  __shared__ __align__(16) f16 As[8192];
  __shared__ __align__(16) f16 Bs[8192];
  int n0 = blockIdx.x * 128;
  int m0 = blockIdx.y * 128;
  int tid = threadIdx.x, lane = tid & 63, w = tid >> 6;
  int wr = (w >> 1) * 64, wc = (w & 1) * 64;
  f32x4 acc[4][4] = {};

  for (int k0 = 0; k0 < 1024; k0 += 64) {
    __syncthreads();
#pragma unroll
    for (int q = 0; q < 4; q++) {
      int ch = tid + q * 256;
      int c = ch >> 7, r = ch & 127;
      gl_lds16(e16 + (size_t)(m0 + r) * 1024 + k0 + c * 8, (char*)As + ch * 16);
    }
#pragma unroll
    for (int q = 0; q < 4; q++) {
      int ch = tid + q * 256;
      int c = ch >> 7, r = ch & 127;
      gl_lds16(w0p + (size_t)(n0 + r) * 1024 + k0 + c * 8, (char*)Bs + ch * 16);
    }
    __syncthreads();
#pragma unroll
    for (int ks = 0; ks < 2; ks++) {
      int cb = ks * 4 + (lane >> 4);
      f16x8 a[4], b[4];
#pragma unroll
      for (int f = 0; f < 4; f++)
        a[f] = *(const f16x8*)(As + (cb * 128 + wr + f * 16 + (lane & 15)) * 8);
#pragma unroll
      for (int g = 0; g < 4; g++)
        b[g] = *(const f16x8*)(Bs + (cb * 128 + wc + g * 16 + (lane & 15)) * 8);
#pragma unroll
      for (int f = 0; f < 4; f++)
#pragma unroll
        for (int g = 0; g < 4; g++)
          acc[f][g] = __builtin_amdgcn_mfma_f32_16x16x32_f16(a[f], b[g], acc[f][g], 0, 0, 0);
    }
  }
  int col = lane & 15, lg = lane >> 4;
#pragma unroll
  for (int f = 0; f < 4; f++)
#pragma unroll
    for (int g = 0; g < 4; g++)
#pragma unroll
      for (int j = 0; j < 4; j++) {
        int row = m0 + wr + f * 16 + lg * 4 + j;
        int c = n0 + wc + g * 16 + col;
        uv[(size_t)row * 16384 + c] = acc[f][g][j];
      }
}

// ---------------- pair activation: h1 int8 [32768][2048] ----------------
// u-part (row b*S+i, left half) is constant across j: hoist it. 1024 blocks:
// block = (bi, jchunk of 32). Reads halved vs per-pair version.
__global__ __launch_bounds__(256) void pair_h1(const float* __restrict__ uv,
                                               const float* __restrict__ bias0,
                                               signed char* __restrict__ h1q) {
  int bi = blockIdx.x >> 2;             // urow = b*128+i
  int jbase = (blockIdx.x & 3) * 32;
  int b = bi >> 7;
  int t = threadIdx.x;
  int u = t * 8;
  int dd = u >> 10, k = u & 1023;
  const float* ub = uv + (size_t)bi * 16384 + dd * 4096 + k;
  const float* bb = bias0 + dd * 4096 + k;
  f32x8 gi0 = *(const f32x8*)(ub);
  f32x8 gc0 = *(const f32x8*)(ub + 2048);
  f32x8 go0 = *(const f32x8*)(ub + 3072);
  f32x8 bi8 = *(const f32x8*)(bb);
  f32x8 bc8 = *(const f32x8*)(bb + 2048);
  f32x8 bo8 = *(const f32x8*)(bb + 3072);
#pragma unroll
  for (int e = 0; e < 8; e++) { gi0[e] += bi8[e]; gc0[e] += bc8[e]; go0[e] += bo8[e]; }
  const float* vbase = uv + (size_t)(b << 7) * 16384 + 8192 + dd * 4096 + k;
  signed char* obase = h1q + ((size_t)bi * 128 + jbase) * 2048 + u;
#pragma unroll 2
  for (int j = 0; j < 32; ++j) {
    const float* vb = vbase + (size_t)(jbase + j) * 16384;
    f32x8 vi = *(const f32x8*)(vb);
    f32x8 vc = *(const f32x8*)(vb + 2048);
    f32x8 vo = *(const f32x8*)(vb + 3072);
    c8x8 ov;
#pragma unroll
    for (int e = 0; e < 8; e++) {
      float gi = gi0[e] + vi[e];
      float gc = gc0[e] + vc[e];
      float go = go0[e] + vo[e];
      float cell = sigm(gi) * tanh_f(gc);
      float hv = sigm(go) * tanh_f(cell);
      ov[e] = (signed char)(int)rintf(hv * 127.f);
    }
    *(c8x8*)(obase + (size_t)j * 2048) = ov;
  }
}

// ---------------- fused layer-1 GEMM (int8) + LSTM cell + FC ----------------
// 3 blocks/CU variant: block 128 rows x 192 cols, 256 thr / 4 waves (wave
// 128x48). BK=64 (32 K-tiles). LDS 52 KB: A 2-deep (8 KB/buf), B 3-deep
// (12 KB/buf) -> 3 blocks/CU = 3 waves/SIMD (TLP to fill MFMA-pipe gaps).
// Single barrier per tile, counted vmcnt(3) (B(t+2) stays in flight).
// Conflict-free paired-row LDS layout (derived, same bank math as R3/R7):
// line L (128 B) holds rows {2L,2L+1}; slot s of line L holds row
// R=2L+(e>>2), chunk c=e&3 where e=s^(L&7). Read: lane (la,lq) wants
// (R=base+la, c=lq) -> s=((la&1)*4+lq)^((la>>1)&7): 8 lanes/slot-group
// = 2/bank = free. Race audit as R10 (buffers written in tile t were last
// read in t-1; reads retired before barrier t-1 since MFMAs consumed them).
__global__ __launch_bounds__(256, 3) void gemm_l1(const signed char* __restrict__ h1q,
                                                  const signed char* __restrict__ w1q,
                                                  const float* __restrict__ bias1,
                                                  const float* __restrict__ fcw,
                                                  float* __restrict__ partial) {
  __shared__ __align__(16) signed char As[2][8192];    // 128 rows x 64 B per buf
  __shared__ __align__(16) signed char Bs[3][12288];   // 192 rows x 64 B per buf
  int ct = blockIdx.x;                  // 0..31  (d = ct>>4, h-block = ct&15)
  int m0 = blockIdx.y * 128;
  int d = ct >> 4;
  int tid = threadIdx.x, lane = tid & 63;
  int wn = tid >> 6;                    // wave: all 128 rows, cols [wn*48,+48)
  int la = lane & 15, lq = lane >> 4;
  int lh = la >> 1, lb = la & 1;
  int sA = (lb * 4 + lq) ^ lh;          // conflict-free slot (see header)

  // staging: LDS chunk ch=(L*8+s); holds row R=2L+(e>>2), chunk c=e&3, e=s^(L&7)
  const signed char* asrc[2]; signed char* adst[2];
#pragma unroll
  for (int q = 0; q < 2; q++) {
    int ch = tid + q * 256, L = ch >> 3, s = ch & 7;
    int e = s ^ (L & 7), R = 2 * L + (e >> 2), c = e & 3;
    asrc[q] = h1q + (size_t)(m0 + R) * 2048 + c * 16;
    adst[q] = &As[0][ch * 16];
  }
  const signed char* bsrc[3]; signed char* bdst[3];
#pragma unroll
  for (int q = 0; q < 3; q++) {
    int ch = tid + q * 256, L = ch >> 3, s = ch & 7;
    int e = s ^ (L & 7), P = 2 * L + (e >> 2), c = e & 3;
    bsrc[q] = w1q + (size_t)(ct * 192 + P) * 2048 + c * 16;
    bdst[q] = &Bs[0][ch * 16];
  }
  auto stageA = [&](int t, int buf) {
#pragma unroll
    for (int q = 0; q < 2; q++) gl_lds16(asrc[q] + t * 64, adst[q] + buf * 8192);
  };
  auto stageB = [&](int t, int buf) {
#pragma unroll
    for (int q = 0; q < 3; q++) gl_lds16(bsrc[q] + t * 64, bdst[q] + buf * 12288);
  };

  i32x4 acc[8][3] = {};
  stageA(0, 0); stageB(0, 0); stageB(1, 1);
  asm volatile("s_waitcnt vmcnt(3)" ::: "memory");   // A(0)+B(0) landed, B(1) flying
  __builtin_amdgcn_s_barrier();

  int ab = 0, bb = 0;
  for (int t = 0; t < 32; ++t) {
    const signed char* Ab = &As[ab][0];
    const signed char* Bb = &Bs[bb][0];
    i32x4 af[8], bf[3];
#pragma unroll
    for (int rf = 0; rf < 8; rf++)
      af[rf] = *(const i32x4*)(Ab + ((rf * 8 + lh) * 8 + sA) * 16);
#pragma unroll
    for (int cf = 0; cf < 3; cf++)
      bf[cf] = *(const i32x4*)(Bb + ((wn * 24 + cf * 8 + lh) * 8 + sA) * 16);
    // prefetch (targets not referenced this tile)
    if (t < 31) stageA(t + 1, ab ^ 1);
    if (t < 30) stageB(t + 2, bb == 0 ? 2 : bb - 1);   // (t+2)%3
    __builtin_amdgcn_s_setprio(1);
#pragma unroll
    for (int rf = 0; rf < 8; rf++)
#pragma unroll
      for (int cf = 0; cf < 3; cf++)
        acc[rf][cf] = __builtin_amdgcn_mfma_i32_16x16x64_i8(af[rf], bf[cf], acc[rf][cf], 0, 0, 0);
    __builtin_amdgcn_s_setprio(0);
    if (t < 30)      { asm volatile("s_waitcnt vmcnt(3)" ::: "memory"); }  // A(t+1),B(t+1) in
    else             { asm volatile("s_waitcnt vmcnt(0)" ::: "memory"); }  // drain tail
    __builtin_amdgcn_sched_barrier(0);
    __builtin_amdgcn_s_barrier();
    ab ^= 1; bb = (bb == 2) ? 0 : bb + 1;
  }

  // epilogue: dequant + LSTM cell + fc dot; reduce 16 lanes (h) then cross-wn
  // via LDS (sred aliases As[0]; tile 31 used As[1]/Bs[1]; no DMA in flight).
  float* sred = (float*)&As[0][0];      // 4*128 floats = 2 KB
  const float S = 1.0f / 516128.0f;     // 1/(127*4064)
  int hcol = (ct & 15) * 64 + wn * 16 + la;
  float bi = bias1[(d * 3 + 0) * 1024 + hcol];
  float bc = bias1[(d * 3 + 1) * 1024 + hcol];
  float bo = bias1[(d * 3 + 2) * 1024 + hcol];
  float wf = fcw[d * 1024 + hcol];
#pragma unroll
  for (int rf = 0; rf < 8; rf++) {
#pragma unroll
    for (int j = 0; j < 4; j++) {
      float gi = (float)acc[rf][0][j] * S + bi;
      float gc = (float)acc[rf][1][j] * S + bc;
      float go = (float)acc[rf][2][j] * S + bo;
      float cell = sigm(gi) * tanh_f(gc);
      float hv = sigm(go) * tanh_f(cell);
      float v = hv * wf;
      v += __shfl_xor(v, 1);
      v += __shfl_xor(v, 2);
      v += __shfl_xor(v, 4);
      v += __shfl_xor(v, 8);
      if (la == 0) sred[wn * 128 + rf * 16 + lq * 4 + j] = v;
    }
  }
  __syncthreads();
  if (tid < 128) {
    float s = sred[tid] + sred[128 + tid] + sred[256 + tid] + sred[384 + tid];
    partial[(size_t)ct * 32768 + m0 + tid] = s;
  }
}

__global__ void reduce_out(const float* __restrict__ partial,
                           const float* __restrict__ fcb,
                           float* __restrict__ out) {
  int m = blockIdx.x * 256 + threadIdx.x;
  float s = fcb[0];
#pragma unroll
  for (int ct = 0; ct < 32; ct++) s += partial[(size_t)ct * 32768 + m];
  out[m] = s;
}

// ---------------- launch ----------------
extern "C" void kernel_launch(void* const* d_in, const int* in_sizes, int n_in,
                              void* d_out, int out_size, void* d_ws, size_t ws_size,
                              hipStream_t stream) {
  const float* x    = (const float*)d_in[0];
  const float* pos  = (const float*)d_in[1];
  const float* w0f  = (const float*)d_in[2];
  const float* bi0f = (const float*)d_in[3];
  const float* bh0f = (const float*)d_in[4];
  const float* w0b  = (const float*)d_in[5];
  const float* bi0b = (const float*)d_in[6];
  const float* bh0b = (const float*)d_in[7];
  const float* w1f  = (const float*)d_in[8];
  const float* bi1f = (const float*)d_in[9];
  const float* bh1f = (const float*)d_in[10];
  const float* w1b  = (const float*)d_in[11];
  const float* bi1b = (const float*)d_in[12];
  const float* bh1b = (const float*)d_in[13];
  const float* fcw  = (const float*)d_in[14];
  const float* fcb  = (const float*)d_in[15];
  float* out = (float*)d_out;

  char* ws = (char*)d_ws;
  f16*   e16   = (f16*)(ws + OFF_E16);
  f16*   w0p   = (f16*)(ws + OFF_W0P);
  float* uv    = (float*)(ws + OFF_UV);
  float* bias0 = (float*)(ws + OFF_B0);
  signed char* w1q = (signed char*)(ws + OFF_W1P);
  float* bias1 = (float*)(ws + OFF_B1);
  signed char* h1q = (signed char*)(ws + OFF_H1);
  float* part  = (float*)(ws + OFF_PART);

  prep_e<<<256, 256, 0, stream>>>(x, pos, e16);
  prep_w0<<<16384, 256, 0, stream>>>(w0f, w0b, w0p);
  prep_w1<<<6144, 256, 0, stream>>>(w1f, w1b, w1q);
  prep_bias<<<56, 256, 0, stream>>>(bi0f, bh0f, bi0b, bh0b, bi1f, bh1f, bi1b, bh1b,
                                    bias0, bias1);
  gemm_l0<<<dim3(128, 2), 256, 0, stream>>>(e16, w0p, uv);
  pair_h1<<<1024, 256, 0, stream>>>(uv, bias0, h1q);
  gemm_l1<<<dim3(32, 256), 256, 0, stream>>>(h1q, w1q, bias1, fcw, part);
  reduce_out<<<128, 256, 0, stream>>>(part, fcb, out);
}